// Round 3
// baseline (152.186 us; speedup 1.0000x reference)
//
#include <hip/hip_runtime.h>
#include <math.h>

#define NN 50000
#define FD 128
#define HDIM 256
#define NE 800000
#define NBR_CAP 512
#define M_CAP 8192
#define TT 7
#define NBLK 256       // grid of fused kernel (1 block/CU -> co-residency guaranteed)
#define TBLK 384       // threads per block (6 waves)
#define TAILB 32       // blocks that continue into the tail phases

// ws byte offsets (all zeroed by the memset node each call)
#define O_DEG      0         // NN floats
#define O_BITMAP   200704    // 1568 words
#define O_NBRCNT   207104
#define O_MCNT     207232
#define O_BAR0     207360
#define O_BAR1     207488
#define O_NBRNODE  207616    // NBR_CAP ints
#define O_NBRW     209664    // NBR_CAP floats
#define O_MS       211712    // M_CAP ints
#define O_MD       244480    // M_CAP ints
#define O_MW       277248    // M_CAP floats
#define O_A1X      310016    // 128 f
#define O_A2X      310528    // 128 f
#define O_A1H      311040    // 256 f
#define O_A2H      312064    // 256 f
#define O_GACC     313088    // 4*256 f
#define O_HBUF     317184    // 2*256 f
#define O_CBUF     319232    // 256 f
#define O_OBUF     320256    // TT f
#define WS_ZERO_BYTES 320512

__device__ __forceinline__ float sigm(float v) { return 1.f / (1.f + expf(-v)); }
__device__ __forceinline__ float dis_of(float dg) {
    return dg > 0.f ? rsqrtf(fmaxf(dg, 1e-20f)) : 0.f;
}

// Device-scope generation barrier (works across XCDs; counter starts 0 each call
// via the memset node, and every barrier adds exactly nb, so old/nb is the gen).
__device__ __forceinline__ void gbar(unsigned* bar, unsigned nb) {
    __syncthreads();
    if (threadIdx.x == 0) {
        __threadfence();   // release: wbL2 so other XCDs can see our stores
        unsigned old = __hip_atomic_fetch_add(bar, 1u, __ATOMIC_ACQ_REL, __HIP_MEMORY_SCOPE_AGENT);
        unsigned tgt = (old / nb + 1u) * nb;
        while (__hip_atomic_load(bar, __ATOMIC_ACQUIRE, __HIP_MEMORY_SCOPE_AGENT) < tgt)
            __builtin_amdgcn_s_sleep(1);
        __threadfence();   // acquire: invalidate L1/L2 before reading others' data
    }
    __syncthreads();
}

__global__ __launch_bounds__(TBLK) void k_fused(
    const float* __restrict__ x, const int* __restrict__ ei, const float* __restrict__ ew,
    const float* __restrict__ h, const float* __restrict__ c,
    const float* __restrict__ theta_x, const float* __restrict__ bias_x,
    const float* __restrict__ theta_h, const float* __restrict__ bias_h,
    const float* __restrict__ w_c, const float* __restrict__ b_gate,
    const float* __restrict__ w_ih, const float* __restrict__ w_hh,
    const float* __restrict__ b_ih, const float* __restrict__ b_hh,
    const float* __restrict__ w_out, const float* __restrict__ b_out,
    float* __restrict__ out, char* __restrict__ ws) {

    float*    deg    = (float*)(ws + O_DEG);
    unsigned* bitmap = (unsigned*)(ws + O_BITMAP);
    int*      nbrCnt = (int*)(ws + O_NBRCNT);
    int*      mCnt   = (int*)(ws + O_MCNT);
    unsigned* bar0   = (unsigned*)(ws + O_BAR0);
    unsigned* bar1   = (unsigned*)(ws + O_BAR1);
    int*      nbrNode= (int*)(ws + O_NBRNODE);
    float*    nbrW   = (float*)(ws + O_NBRW);
    int*      mS     = (int*)(ws + O_MS);
    int*      mD     = (int*)(ws + O_MD);
    float*    mW     = (float*)(ws + O_MW);
    float*    A1x    = (float*)(ws + O_A1X);
    float*    A2x    = (float*)(ws + O_A2X);
    float*    A1h    = (float*)(ws + O_A1H);
    float*    A2h    = (float*)(ws + O_A2H);
    float*    gacc   = (float*)(ws + O_GACC);
    float*    hbuf   = (float*)(ws + O_HBUF);
    float*    cbuf   = (float*)(ws + O_CBUF);
    float*    obuf   = (float*)(ws + O_OBUF);

    __shared__ int   sNode[NBR_CAP];
    __shared__ float sW[NBR_CAP];
    __shared__ float tx[3 * FD];
    __shared__ float th[3 * HDIM];
    __shared__ float wsh[32 * 260];      // w_hh rows for this block, +4 pad per row
    __shared__ float sh[HDIM];
    __shared__ float sdot[32];
    __shared__ float sinp;
    __shared__ int   sCnt, sMcnt;

    const int tid = threadIdx.x, bid = blockIdx.x;
    const int STRIDE = NBLK * TBLK * 4;

    // ---------------- phase 1: scan dst column, collect in-neighbors of node 0 ----
    for (int e0 = (bid * TBLK + tid) * 4; e0 < NE; e0 += STRIDE) {
        int4 d4 = *(const int4*)&ei[NE + e0];
        float4 w4 = *(const float4*)&ew[e0];
        int dd[4] = {d4.x, d4.y, d4.z, d4.w};
        float wv[4] = {w4.x, w4.y, w4.z, w4.w};
        #pragma unroll
        for (int k = 0; k < 4; ++k) {
            if (dd[k] == 0 && wv[k] != 0.f) {
                int s = ei[e0 + k];
                if (s != 0) {
                    int slot = atomicAdd(nbrCnt, 1);
                    if (slot < NBR_CAP) { nbrNode[slot] = s; nbrW[slot] = wv[k]; }
                }
            }
        }
    }
    gbar(bar0, NBLK);

    // load nbr list into LDS (every block)
    if (tid == 0) sCnt = min(*nbrCnt, NBR_CAP);
    __syncthreads();
    const int ncnt = sCnt;
    for (int i = tid; i < ncnt; i += TBLK) { sNode[i] = nbrNode[i]; sW[i] = nbrW[i]; }
    if (bid == 0 && tid == 0) atomicOr(&bitmap[0], 1u);     // deg[0] is needed
    __syncthreads();

    // ---------------- phase 2: match edges into the 2-hop set, mark needed nodes --
    for (int e0 = (bid * TBLK + tid) * 4; e0 < NE; e0 += STRIDE) {
        int4 s4 = *(const int4*)&ei[e0];
        int4 d4 = *(const int4*)&ei[NE + e0];
        float4 w4 = *(const float4*)&ew[e0];
        int ss[4] = {s4.x, s4.y, s4.z, s4.w};
        int dd[4] = {d4.x, d4.y, d4.z, d4.w};
        float wv[4] = {w4.x, w4.y, w4.z, w4.w};
        bool m[4];
        #pragma unroll
        for (int k = 0; k < 4; ++k) m[k] = (dd[k] == 0);
        for (int j = 0; j < ncnt; ++j) {
            int nv = sNode[j];
            #pragma unroll
            for (int k = 0; k < 4; ++k) m[k] |= (dd[k] == nv);
        }
        #pragma unroll
        for (int k = 0; k < 4; ++k) {
            int s = ss[k], d = dd[k];
            float w = wv[k];
            if (s == d || w == 0.f || !m[k]) continue;
            int slot = atomicAdd(mCnt, 1);
            if (slot < M_CAP) { mS[slot] = s; mD[slot] = d; mW[slot] = w; }
            atomicOr(&bitmap[s >> 5], 1u << (s & 31));
            atomicOr(&bitmap[d >> 5], 1u << (d & 31));
        }
    }
    gbar(bar0, NBLK);

    // ---------------- phase 3: deg only for bitmap-marked srcs ---------------------
    for (int e0 = (bid * TBLK + tid) * 4; e0 < NE; e0 += STRIDE) {
        int4 s4 = *(const int4*)&ei[e0];
        int4 d4 = *(const int4*)&ei[NE + e0];
        float4 w4 = *(const float4*)&ew[e0];
        int ss[4] = {s4.x, s4.y, s4.z, s4.w};
        int dd[4] = {d4.x, d4.y, d4.z, d4.w};
        float wv[4] = {w4.x, w4.y, w4.z, w4.w};
        #pragma unroll
        for (int k = 0; k < 4; ++k) {
            int s = ss[k];
            if (s == dd[k] || wv[k] == 0.f) continue;
            if (bitmap[s >> 5] & (1u << (s & 31)))
                atomicAdd(&deg[s], wv[k]);
        }
    }
    gbar(bar0, NBLK);

    if (bid >= TAILB) return;           // tail runs on 32 blocks; bar1 only below

    // ---------------- accum: A1/A2 over matched edges ------------------------------
    if (tid == 0) sMcnt = min(*mCnt, M_CAP);
    __syncthreads();
    {
        const int cnt = sMcnt;
        const float dis0 = dis_of(deg[0]);
        float a1 = 0.f, a2 = 0.f;
        for (int i = bid; i < cnt; i += TAILB) {
            int s = mS[i], d = mD[i];
            float w = mW[i];
            float diss = dis_of(deg[s]);
            float disd = dis_of(deg[d]);
            float wn = diss * w * disd;
            float c1 = (d == 0) ? wn : 0.f;
            float Wd = 0.f;
            for (int j = 0; j < ncnt; ++j) Wd += (sNode[j] == d) ? sW[j] : 0.f;
            float c2 = wn * (dis0 * disd * Wd);
            float v = (tid < FD) ? x[(size_t)s * FD + tid] : h[(size_t)s * HDIM + (tid - FD)];
            a1 += c1 * v;
            a2 += c2 * v;
        }
        if (tid < FD) { atomicAdd(&A1x[tid], a1); atomicAdd(&A2x[tid], a2); }
        else          { atomicAdd(&A1h[tid - FD], a1); atomicAdd(&A2h[tid - FD], a2); }
    }
    gbar(bar1, TAILB);                  // B1

    // ---------------- gemv: gacc[g][o] ---------------------------------------------
    for (int i = tid; i < FD; i += TBLK) {
        float x0 = x[i];
        tx[i] = x0;
        tx[FD + i] = -A1x[i];                    // T1 = -A1
        tx[2 * FD + i] = 2.f * A2x[i] - x0;      // T2 = 2*lhat(T1) - T0
    }
    for (int i = tid; i < HDIM; i += TBLK) {
        float h0 = h[i];
        th[i] = h0;
        th[HDIM + i] = -A1h[i];
        th[2 * HDIM + i] = 2.f * A2h[i] - h0;
    }
    __syncthreads();
    if (tid < HDIM) {
        const int g = bid >> 3, chunk = bid & 7;
        const int PX = 3 * FD, PTOT = PX + 3 * HDIM, CH = PTOT / 8;
        float acc = 0.f;
        for (int p = chunk * CH; p < (chunk + 1) * CH; ++p) {
            float tval;
            const float* row;
            if (p < PX) { tval = tx[p]; row = theta_x + ((size_t)(g * PX + p)) * HDIM; }
            else { int q = p - PX; tval = th[q]; row = theta_h + ((size_t)(g * 3 * HDIM + q)) * HDIM; }
            acc += tval * row[tid];
        }
        atomicAdd(&gacc[g * HDIM + tid], acc);
    }
    gbar(bar1, TAILB);                  // B2

    // ---------------- gates (block 0) + per-block preloads --------------------------
    if (bid == 0 && tid < HDIM) {
        int o = tid;
        float g0 = gacc[0 * HDIM + o] + bias_x[0 * HDIM + o] + bias_h[0 * HDIM + o];
        float g1 = gacc[1 * HDIM + o] + bias_x[1 * HDIM + o] + bias_h[1 * HDIM + o];
        float g2 = gacc[2 * HDIM + o] + bias_x[2 * HDIM + o] + bias_h[2 * HDIM + o];
        float g3 = gacc[3 * HDIM + o] + bias_x[3 * HDIM + o] + bias_h[3 * HDIM + o];
        float c0 = c[o];
        float I  = sigm(g0 + w_c[0 * HDIM + o] * c0 + b_gate[0 * HDIM + o]);
        float Fg = sigm(g1 + w_c[1 * HDIM + o] * c0 + b_gate[1 * HDIM + o]);
        float Cn = Fg * c0 + I * tanhf(g2 + b_gate[2 * HDIM + o]);
        float O  = sigm(g3 + w_c[2 * HDIM + o] * Cn + b_gate[3 * HDIM + o]);
        hbuf[o] = O * tanhf(Cn);                 // slot 0
        cbuf[o] = Cn;
    }
    // stage this block's 32 w_hh rows into LDS (rows strip*256 + bid*8 + lt)
    for (int idx = tid; idx < 32 * HDIM; idx += TBLK) {
        int rl = idx >> 8, k = idx & 255;
        int row = (rl >> 3) * HDIM + bid * 8 + (rl & 7);
        wsh[rl * 260 + k] = w_hh[(size_t)row * HDIM + k];
    }
    const int rl = tid >> 3, part = tid & 7;
    float wih_r = 0.f, b_r = 0.f;
    if (tid < 256 && part == 0) {
        int row = (rl >> 3) * HDIM + bid * 8 + (rl & 7);
        wih_r = w_ih[row];
        b_r = b_ih[row] + b_hh[row];
    }
    float creg = 0.f, wout_r = 0.f;
    const int tg = bid * 8 + (tid & 7);
    if (tid < 8) wout_r = w_out[tg];
    const float bo = b_out[0];
    gbar(bar1, TAILB);                  // B3

    // ---------------- 7 LSTM steps --------------------------------------------------
    for (int t = 0; t < TT; ++t) {
        const float* hr = hbuf + (t & 1) * HDIM;
        float* hw = hbuf + ((t + 1) & 1) * HDIM;
        if (tid < 64) *(float4*)&sh[tid * 4] = *(const float4*)&hr[tid * 4];
        if (tid == 0) sinp = (t == 0) ? x[FD - 1] : (obuf[t - 1] + bo);
        __syncthreads();
        if (tid < 256) {
            const float* wrow = &wsh[rl * 260 + part * 32];
            const float* shh = &sh[part * 32];
            float acc = 0.f;
            #pragma unroll
            for (int d0 = 0; d0 < 32; d0 += 4) {
                float4 wv = *(const float4*)&wrow[d0];
                acc += shh[d0] * wv.x + shh[d0 + 1] * wv.y
                     + shh[d0 + 2] * wv.z + shh[d0 + 3] * wv.w;
            }
            acc += __shfl_down(acc, 4);
            acc += __shfl_down(acc, 2);
            acc += __shfl_down(acc, 1);
            if (part == 0) sdot[rl] = acc + sinp * wih_r + b_r;
        }
        __syncthreads();
        if (tid < 8) {
            if (t == 0) creg = cbuf[tg];
            float iv = sdot[tid], fv = sdot[8 + tid], gv = sdot[16 + tid], ov = sdot[24 + tid];
            float cn = sigm(fv) * creg + sigm(iv) * tanhf(gv);
            float hn = sigm(ov) * tanhf(cn);
            creg = cn;
            hw[tg] = hn;
            float po = hn * wout_r;
            po += __shfl_down(po, 4);
            po += __shfl_down(po, 2);
            po += __shfl_down(po, 1);
            if (tid == 0) atomicAdd(&obuf[t], po);
        }
        gbar(bar1, TAILB);              // per-step barrier
    }

    if (bid == 0 && tid < TT) out[tid] = obuf[tid] + bo;
}

extern "C" void kernel_launch(void* const* d_in, const int* in_sizes, int n_in,
                              void* d_out, int out_size, void* d_ws, size_t ws_size,
                              hipStream_t stream) {
    const float* x       = (const float*)d_in[0];
    const int*   ei      = (const int*)d_in[1];
    const float* ew      = (const float*)d_in[2];
    const float* h       = (const float*)d_in[3];
    const float* c       = (const float*)d_in[4];
    const float* theta_x = (const float*)d_in[5];
    const float* bias_x  = (const float*)d_in[6];
    const float* theta_h = (const float*)d_in[7];
    const float* bias_h  = (const float*)d_in[8];
    const float* w_c     = (const float*)d_in[9];
    const float* b_gate  = (const float*)d_in[10];
    const float* w_ih    = (const float*)d_in[11];
    const float* w_hh    = (const float*)d_in[12];
    const float* b_ih    = (const float*)d_in[13];
    const float* b_hh    = (const float*)d_in[14];
    const float* w_out   = (const float*)d_in[15];
    const float* b_out   = (const float*)d_in[16];

    hipMemsetAsync(d_ws, 0, WS_ZERO_BYTES, stream);
    k_fused<<<NBLK, TBLK, 0, stream>>>(x, ei, ew, h, c, theta_x, bias_x, theta_h, bias_h,
                                       w_c, b_gate, w_ih, w_hh, b_ih, b_hh, w_out, b_out,
                                       (float*)d_out, (char*)d_ws);
}